// Round 14
// baseline (254.825 us; speedup 1.0000x reference)
//
#include <hip/hip_runtime.h>
#include <cmath>

// PSNR + 3D-SSIM, pred/gt (N=4, C=16->D, H=512, W=512) f32.
// R22 = R20's math verbatim (best accuracy 0.0067, 155us) with the SCHEDULE
// changed: R16/R20/R21 all pinned at 154-155us with no pipe >60% busy and
// VALU-work-invariant duration -> the floor is the 32-barrier lockstep, not
// a throughput pipe. This round software-pipelines the phases:
//   region d = { stage(d+1) -> sd[(d+1)&1] | prefetch(d+2) |
//                H(d): sd[d&1] -> tmp[d&1] | W(d-1)+Dacc(d-1): tmp[(d-1)&1] }
//   -> ONE barrier per slice (17 total, was 32). Both sd and tmp are
//   parity double-buffered (13 KB); every producer/consumer pair is
//   separated by exactly one barrier via the parity flip.
// Each region now mixes LDS reads+writes, global loads, and ~130 VALU ops
// -> the per-CU VALU (~85us) and LDS (~87us) budgets can finally overlap.

#define NB 4
#define DD 16
#define HH 512
#define WW 512
#define SLICE (HH * WW)
#define VOL (DD * SLICE)
#define C1F 0.0001f
#define C2F 0.0009f

#define TH 16
#define TW 16
#define SCOLS 26            // staged cols (TW+10)
#define NRP 13              // staged row-pairs ((TH+10)/2)
#define PW 14               // words per col-parity plane (13 + pad)
#define PLSTR 28            // row-pair stride (2 planes)
#define SDW (NRP * PLSTR)   // 364 uint2 per buffer
#define TMW (TH * PW)       // 224 uint4 per buffer
#define NTHR 256
#define SIT (NRP * SCOLS)   // 338 stage items per slice
#define XTRA (SIT - NTHR)   // 82
#define HITEMS 104          // 8 out-row-pairs x 13 col-pairs

typedef _Float16 h2v __attribute__((ext_vector_type(2)));

struct KArg {
  unsigned ge[6], go[6];   // f16x2 tap-pair coeffs, even/odd phase (renorm'd)
  float wlT[DD * DD];      // wlT[d*16+dout] = clamp-folded D weight (f32)
};

__device__ inline float dot2h(unsigned a, unsigned b, float c) {
#if __has_builtin(__builtin_amdgcn_fdot2)
  return __builtin_amdgcn_fdot2(__builtin_bit_cast(h2v, a),
                                __builtin_bit_cast(h2v, b), c, false);
#else
  h2v av = __builtin_bit_cast(h2v, a), bv = __builtin_bit_cast(h2v, b);
  return fmaf((float)av.y, (float)bv.y, fmaf((float)av.x, (float)bv.x, c));
#endif
}
__device__ inline unsigned pkh(float a, float b) {
  return __builtin_bit_cast(unsigned, __builtin_amdgcn_cvt_pkrtz(a, b));
}
__device__ inline unsigned pk2sq(unsigned a) {   // element-wise f16x2 square
  h2v v = __builtin_bit_cast(h2v, a);
  v = v * v;                                     // v_pk_mul_f16
  return __builtin_bit_cast(unsigned, v);
}
__device__ inline int iclamp(int v, int lo, int hi) {
  return v < lo ? lo : (v > hi ? hi : v);
}

__device__ inline float block_sum256(float v) {
#pragma unroll
  for (int o = 32; o > 0; o >>= 1) v += __shfl_down(v, o, 64);
  __shared__ float r[4];
  if ((threadIdx.x & 63) == 0) r[threadIdx.x >> 6] = v;
  __syncthreads();
  float out = 0.f;
  if (threadIdx.x == 0) {
#pragma unroll
    for (int i = 0; i < 4; ++i) out += r[i];
  }
  __syncthreads();
  return out;
}

__global__ void zero_acc_k(float* acc) {
  if (threadIdx.x < 8) acc[threadIdx.x] = 0.f;
}

__global__ __launch_bounds__(NTHR, 3) void fused_k(
    const float* __restrict__ pred, const float* __restrict__ gt,
    float* __restrict__ acc, KArg ka) {
  __shared__ uint2 sd[2 * SDW];    // staged {S,D}, parity dbuf   5.8 KB
  __shared__ uint4 tmp[2 * TMW];   // H-blurred, parity dbuf      7.2 KB

  // XCD-aware bijective swizzle (kept from R16: FETCH 257->78 MB)
  int b0 = blockIdx.x;
  int b = (b0 & 7) * ((NB * 1024) >> 3) + (b0 >> 3);
  int tile = b & 1023;               // 32 h-tiles x 32 w-tiles
  int n = b >> 10;
  int th0 = (tile >> 5) * TH;
  int tw0 = (tile & 31) * TW;
  int t = threadIdx.x;

  // ---- stage metadata, slot 0 (item t, always < 338)
  int rp0 = t / SCOLS, x0 = t - rp0 * SCOLS;
  int gx0 = iclamp(tw0 + x0 - 5, 0, WW - 1);
  int go0a = iclamp(th0 + 2 * rp0 - 5, 0, HH - 1) * WW + gx0;
  int go0b = iclamp(th0 + 2 * rp0 - 4, 0, HH - 1) * WW + gx0;
  int w0i = (2 * rp0 + (x0 & 1)) * PW + (x0 >> 1);
  bool ox0 = (x0 >= 5) && (x0 < 5 + TW);
  float o0a = (ox0 && rp0 >= 3 && rp0 <= 10) ? 1.f : 0.f;  // row 2rp-5 owned
  float o0b = (ox0 && rp0 >= 2 && rp0 <= 9) ? 1.f : 0.f;   // row 2rp-4 owned
  // slot 1 (items 256..337 -> threads 174..255)
  int i1 = t + XTRA;
  bool has2 = (i1 >= NTHR);
  int rp1 = i1 / SCOLS, x1 = i1 - rp1 * SCOLS;
  int gx1 = iclamp(tw0 + x1 - 5, 0, WW - 1);
  int go1a = iclamp(th0 + 2 * rp1 - 5, 0, HH - 1) * WW + gx1;
  int go1b = iclamp(th0 + 2 * rp1 - 4, 0, HH - 1) * WW + gx1;
  int w1i = (2 * rp1 + (x1 & 1)) * PW + (x1 >> 1);
  bool ox1 = (x1 >= 5) && (x1 < 5 + TW);
  float o1a = (ox1 && rp1 >= 3 && rp1 <= 10) ? 1.f : 0.f;
  float o1b = (ox1 && rp1 >= 2 && rp1 <= 9) ? 1.f : 0.f;

  // ---- H metadata: item = (out-row-pair hm, col-pair hcp), m-minor
  bool hasH = (t < HITEMS);
  int hm = t & 7, hcp = t >> 3;
  int hrd = hm * PLSTR + hcp;        // plane0 read base (tap J adds J*PLSTR)
  int hwr = (2 * hm) * PW + hcp;     // row 2m write (+PW for row 2m+1)

  // ---- W metadata: thread owns px (t>>4, t&15) -- broadcast-pair reads
  int wx = t & 15;
  int wrd = (t >> 4) * PW + (wx >> 1);
  unsigned cw[6];
#pragma unroll
  for (int J = 0; J < 6; ++J) cw[J] = (wx & 1) ? ka.go[J] : ka.ge[J];

  const float* pb = pred + (size_t)n * VOL;
  const float* qb = gt + (size_t)n * VOL;

  float psnr = 0.f;
  float a0[DD], a1[DD], a2[DD], a3[DD];
#pragma unroll
  for (int j = 0; j < DD; ++j) { a0[j] = a1[j] = a2[j] = a3[j] = 0.f; }

  // ---- prologue: load slice 0, stage(0) -> sd[0], load slice 1, barrier
  float p0a = pb[go0a], p0b = pb[go0b], q0a = qb[go0a], q0b = qb[go0b];
  float p1a = 0.f, p1b = 0.f, q1a = 0.f, q1b = 0.f;
  if (has2) { p1a = pb[go1a]; p1b = pb[go1b]; q1a = qb[go1a]; q1b = qb[go1b]; }
  {
    float SA = p0a + q0a, DA = p0a - q0a;
    float SB = p0b + q0b, DB = p0b - q0b;
    psnr = fmaf(o0a, DA * DA, psnr);
    psnr = fmaf(o0b, DB * DB, psnr);
    sd[w0i] = make_uint2(pkh(SA, SB), pkh(DA, DB));
  }
  if (has2) {
    float SA = p1a + q1a, DA = p1a - q1a;
    float SB = p1b + q1b, DB = p1b - q1b;
    psnr = fmaf(o1a, DA * DA, psnr);
    psnr = fmaf(o1b, DB * DB, psnr);
    sd[w1i] = make_uint2(pkh(SA, SB), pkh(DA, DB));
  }
  {
    const float* P = pb + SLICE;
    const float* Q = qb + SLICE;
    p0a = P[go0a]; p0b = P[go0b]; q0a = Q[go0a]; q0b = Q[go0b];
    if (has2) { p1a = P[go1a]; p1b = P[go1b]; q1a = Q[go1a]; q1b = Q[go1b]; }
  }
  __syncthreads();

  float ww0, ww1, ww2, ww3;

  // ---- pipelined main loop: ONE barrier per slice
#pragma unroll 1
  for (int d = 0; d < DD; ++d) {
    uint2* sdn = sd + ((d + 1) & 1) * SDW;   // stage target
    const uint2* sdc = sd + (d & 1) * SDW;   // H source
    uint4* tmc = tmp + (d & 1) * TMW;        // H target
    const uint4* tmr = tmp + ((d + 1) & 1) * TMW;  // W source = (d-1)&1

    // stage(d+1) from regs (slice d+1), then prefetch(d+2) into same regs
    if (d < DD - 1) {
      {
        float SA = p0a + q0a, DA = p0a - q0a;
        float SB = p0b + q0b, DB = p0b - q0b;
        psnr = fmaf(o0a, DA * DA, psnr);
        psnr = fmaf(o0b, DB * DB, psnr);
        sdn[w0i] = make_uint2(pkh(SA, SB), pkh(DA, DB));
      }
      if (has2) {
        float SA = p1a + q1a, DA = p1a - q1a;
        float SB = p1b + q1b, DB = p1b - q1b;
        psnr = fmaf(o1a, DA * DA, psnr);
        psnr = fmaf(o1b, DB * DB, psnr);
        sdn[w1i] = make_uint2(pkh(SA, SB), pkh(DA, DB));
      }
      if (d < DD - 2) {
        const float* P = pb + (size_t)(d + 2) * SLICE;
        const float* Q = qb + (size_t)(d + 2) * SLICE;
        p0a = P[go0a]; p0b = P[go0b]; q0a = Q[go0a]; q0b = Q[go0b];
        if (has2) { p1a = P[go1a]; p1b = P[go1b]; q1a = Q[go1a]; q1b = Q[go1b]; }
      }
    }

    // W(d-1) + D-accumulate(d-1) from tmp[(d-1)&1]
    if (d >= 1) {
      ww0 = 0.f; ww1 = 0.f; ww2 = 0.f; ww3 = 0.f;
#pragma unroll
      for (int J = 0; J < 6; ++J) {
        uint4 v = tmr[wrd + J];
        ww0 = dot2h(cw[J], v.x, ww0); ww1 = dot2h(cw[J], v.y, ww1);
        ww2 = dot2h(cw[J], v.z, ww2); ww3 = dot2h(cw[J], v.w, ww3);
      }
      const float* wl = ka.wlT + (d - 1) * DD;
#pragma unroll
      for (int o = 0; o < DD; ++o) {
        float w = wl[o];
        a0[o] = fmaf(w, ww0, a0[o]);
        a1[o] = fmaf(w, ww1, a1[o]);
        a2[o] = fmaf(w, ww2, a2[o]);
        a3[o] = fmaf(w, ww3, a3[o]);
      }
    }

    // H(d): sd[d&1] -> tmp[d&1] (squares formed in-register)
    if (hasH) {
      float e0[4] = {0, 0, 0, 0}, e1[4] = {0, 0, 0, 0};
      float r0[4] = {0, 0, 0, 0}, r1[4] = {0, 0, 0, 0};
#pragma unroll
      for (int J = 0; J < 6; ++J) {
        uint2 ve = sdc[hrd + J * PLSTR];
        uint2 vo = sdc[hrd + J * PLSTR + PW];
        unsigned ves = pk2sq(ve.x), ved = pk2sq(ve.y);
        unsigned vos = pk2sq(vo.x), vod = pk2sq(vo.y);
        unsigned cge = ka.ge[J], cgo = ka.go[J];
        e0[0] = dot2h(cge, ve.x, e0[0]); e0[1] = dot2h(cge, ve.y, e0[1]);
        e0[2] = dot2h(cge, ves, e0[2]);  e0[3] = dot2h(cge, ved, e0[3]);
        r0[0] = dot2h(cgo, ve.x, r0[0]); r0[1] = dot2h(cgo, ve.y, r0[1]);
        r0[2] = dot2h(cgo, ves, r0[2]);  r0[3] = dot2h(cgo, ved, r0[3]);
        e1[0] = dot2h(cge, vo.x, e1[0]); e1[1] = dot2h(cge, vo.y, e1[1]);
        e1[2] = dot2h(cge, vos, e1[2]);  e1[3] = dot2h(cge, vod, e1[3]);
        r1[0] = dot2h(cgo, vo.x, r1[0]); r1[1] = dot2h(cgo, vo.y, r1[1]);
        r1[2] = dot2h(cgo, vos, r1[2]);  r1[3] = dot2h(cgo, vod, r1[3]);
      }
      tmc[hwr] = make_uint4(pkh(e0[0], e1[0]), pkh(e0[1], e1[1]),
                            pkh(e0[2], e1[2]), pkh(e0[3], e1[3]));
      tmc[hwr + PW] = make_uint4(pkh(r0[0], r1[0]), pkh(r0[1], r1[1]),
                                 pkh(r0[2], r1[2]), pkh(r0[3], r1[3]));
    }

    __syncthreads();   // the ONLY barrier: flips all parities safely
  }

  // ---- epilogue region: W(15) + D-accumulate(15) from tmp[15&1]
  {
    const uint4* tmr = tmp + (15 & 1) * TMW;
    ww0 = 0.f; ww1 = 0.f; ww2 = 0.f; ww3 = 0.f;
#pragma unroll
    for (int J = 0; J < 6; ++J) {
      uint4 v = tmr[wrd + J];
      ww0 = dot2h(cw[J], v.x, ww0); ww1 = dot2h(cw[J], v.y, ww1);
      ww2 = dot2h(cw[J], v.z, ww2); ww3 = dot2h(cw[J], v.w, ww3);
    }
    const float* wl = ka.wlT + 15 * DD;
#pragma unroll
    for (int o = 0; o < DD; ++o) {
      float w = wl[o];
      a0[o] = fmaf(w, ww0, a0[o]);
      a1[o] = fmaf(w, ww1, a1[o]);
      a2[o] = fmaf(w, ww2, a2[o]);
      a3[o] = fmaf(w, ww3, a3[o]);
    }
  }

  // ---- SSIM over the 16 douts of this px
  float ssum = 0.f;
#pragma unroll
  for (int j = 0; j < DD; ++j) {
    float Sb = a0[j], Db = a1[j], B1 = a2[j], B2 = a3[j];
    float SS = Sb * Sb, DDm = Db * Db;
    float m12_2 = (SS - DDm) * 0.5f;     // 2*mu1*mu2
    float msq   = (SS + DDm) * 0.5f;     // mu1^2 + mu2^2
    float Epq   = (B1 - B2) * 0.25f;     // E[pq]
    float Esum  = (B1 + B2) * 0.5f;      // E[p^2+q^2]
    float sig12_2 = 2.f * Epq - m12_2;   // 2*sigma12
    float svar    = Esum - msq;          // sigma1^2 + sigma2^2
    float num = (m12_2 + C1F) * (sig12_2 + C2F);
    float den = (msq + C1F) * (svar + C2F);
    ssum += num / den;
  }
  float bs = block_sum256(ssum);
  if (t == 0) atomicAdd(&acc[4 + n], bs);
  float bp = block_sum256(psnr);
  if (t == 0) atomicAdd(&acc[n], bp);
}

__global__ void final_k(const float* __restrict__ acc, float* __restrict__ out) {
  if (threadIdx.x == 0 && blockIdx.x == 0) {
    double psnr = 0.0, ssim = 0.0;
    for (int n = 0; n < NB; ++n) {
      double mse = (double)acc[n] / (double)VOL;
      psnr += 10.0 * log10(1.0 / mse);
      ssim += (double)acc[4 + n] / (double)VOL;
    }
    out[0] = (float)psnr;
    out[1] = (float)ssim;
    out[2] = (float)NB;
  }
}

// host f32 -> f16 (round-to-nearest-even)
static unsigned short f2h(float f) {
  union { float f; unsigned u; } v; v.f = f;
  unsigned u = v.u;
  unsigned s = (u >> 16) & 0x8000u;
  int e = (int)((u >> 23) & 0xff) - 127 + 15;
  unsigned m = u & 0x7fffffu;
  if (e <= 0) return (unsigned short)s;
  if (e >= 31) return (unsigned short)(s | 0x7c00u);
  unsigned h = ((unsigned)e << 10) | (m >> 13);
  unsigned rem = m & 0x1fffu;
  if (rem > 0x1000u || (rem == 0x1000u && (h & 1u))) h++;
  return (unsigned short)(s | h);
}
// host f16 -> f32 (normals + zero)
static float h2f(unsigned short h) {
  unsigned se = (h >> 10) & 0x1f, m = h & 0x3ffu, s = ((unsigned)h & 0x8000u) << 16;
  union { unsigned u; float f; } v;
  if (se == 0) { v.u = s; return v.f; }
  v.u = s | ((se - 15 + 127) << 23) | (m << 13);
  return v.f;
}

extern "C" void kernel_launch(void* const* d_in, const int* in_sizes, int n_in,
                              void* d_out, int out_size, void* d_ws, size_t ws_size,
                              hipStream_t stream) {
  const float* pred = (const float*)d_in[0];
  const float* gt = (const float*)d_in[1];
  float* acc = (float*)d_ws;    // 8 floats

  double tt[11], s = 0.0;
  for (int i = 0; i < 11; ++i) {
    double x = i - 5;
    tt[i] = exp(-(x * x) / 4.5);
    s += tt[i];
  }
  float g[11];
  for (int i = 0; i < 11; ++i) g[i] = (float)(tt[i] / s);

  // f16 taps renormalized so the f16 values sum exactly to 1
  unsigned short hg[11];
  for (int i = 0; i < 11; ++i) hg[i] = f2h(g[i]);
  for (int pass = 0; pass < 3; ++pass) {
    double sum = 0.0;
    for (int i = 0; i < 11; ++i) sum += (double)h2f(hg[i]);
    hg[5] = f2h((float)((double)h2f(hg[5]) + (1.0 - sum)));
  }

  KArg ka;
  // even phase: (g0,g1)(g2,g3)(g4,g5)(g6,g7)(g8,g9)(g10,0)
  for (int j = 0; j < 5; ++j)
    ka.ge[j] = (unsigned)hg[2 * j] | ((unsigned)hg[2 * j + 1] << 16);
  ka.ge[5] = (unsigned)hg[10];
  // odd phase: (0,g0)(g1,g2)(g3,g4)(g5,g6)(g7,g8)(g9,g10)
  ka.go[0] = ((unsigned)hg[0]) << 16;
  for (int j = 1; j < 6; ++j)
    ka.go[j] = (unsigned)hg[2 * j - 1] | ((unsigned)hg[2 * j] << 16);

  // clamp-folded D-blur weights, f32, transposed: wlT[d][dout]
  for (int o = 0; o < DD; ++o)
    for (int d = 0; d < DD; ++d) {
      float w = 0.f;
      for (int k = 0; k < 11; ++k) {
        int j = o + k - 5;
        j = j < 0 ? 0 : (j > 15 ? 15 : j);
        if (j == d) w += g[k];
      }
      ka.wlT[d * DD + o] = w;
    }

  zero_acc_k<<<1, 64, 0, stream>>>(acc);
  fused_k<<<NB * 1024, NTHR, 0, stream>>>(pred, gt, acc, ka);
  final_k<<<1, 1, 0, stream>>>(acc, (float*)d_out);
}

// Round 15
// 238.777 us; speedup vs baseline: 1.0672x; 1.0672x over previous
//
#include <hip/hip_runtime.h>
#include <cmath>

// PSNR + 3D-SSIM, pred/gt (N=4, C=16->D, H=512, W=512) f32.
// R23 = R20 (tied-best 154.5us, absmax 0.0067) + f16x2 PACKED ACCUMULATORS.
// Root cause of the 154-159us plateau (5 structurally different schedules,
// work-invariant): gfx950's unified VGPR/AGPR file. The 64 f32 accumulators
// are AGPRs NOT counted in VGPR_Count; true usage = 68+64 = 132 regs ->
// hard 3 waves/SIMD. Cross-check: R17 (64+64=128) was the ONLY round the
// occupancy jumped (39.7%). At 3 waves/SIMD the ~50% VALU and ~50% LDS
// pipes can't overlap -> latency-bound, invariant duration.
// Fix: accumulators -> 32 f16x2 regs (A01={a0,a1}, A23={a2,a3}), accumulate
// via v_pk_fma_f16 (full rate): 2 pkh + 32 pk_fma per slice (was 64 fma).
// Total ~100-104 regs -> 4-5 waves/SIMD. Weights = f16 splat pairs
// (per-dout renorm'd, validated). Expected absmax ~0.01 (f16 acc error
// ~2e-3; rounds at 0.0153 passed repeatedly).

#define NB 4
#define DD 16
#define HH 512
#define WW 512
#define SLICE (HH * WW)
#define VOL (DD * SLICE)
#define C1F 0.0001f
#define C2F 0.0009f

#define TH 16
#define TW 16
#define SCOLS 26            // staged cols (TW+10)
#define NRP 13              // staged row-pairs ((TH+10)/2)
#define PW 14               // words per col-parity plane (13 + pad)
#define PLSTR 28            // row-pair stride (2 planes)
#define SDW (NRP * PLSTR)   // 364 uint2 = 2912 B
#define TMW (TH * PW)       // 224 uint4 = 3584 B
#define NTHR 256
#define SIT (NRP * SCOLS)   // 338 stage items per slice
#define XTRA (SIT - NTHR)   // 82
#define HITEMS 104          // 8 out-row-pairs x 13 col-pairs

typedef _Float16 h2v __attribute__((ext_vector_type(2)));

struct KArg {
  unsigned ge[6], go[6];   // f16x2 tap-pair coeffs, even/odd phase (renorm'd)
  unsigned wl2[DD * DD];   // [d*16+o] = f16x2 splat (w,w), per-dout renorm'd
};

__device__ inline float dot2h(unsigned a, unsigned b, float c) {
#if __has_builtin(__builtin_amdgcn_fdot2)
  return __builtin_amdgcn_fdot2(__builtin_bit_cast(h2v, a),
                                __builtin_bit_cast(h2v, b), c, false);
#else
  h2v av = __builtin_bit_cast(h2v, a), bv = __builtin_bit_cast(h2v, b);
  return fmaf((float)av.y, (float)bv.y, fmaf((float)av.x, (float)bv.x, c));
#endif
}
__device__ inline unsigned pkh(float a, float b) {
  return __builtin_bit_cast(unsigned, __builtin_amdgcn_cvt_pkrtz(a, b));
}
__device__ inline unsigned pk2sq(unsigned a) {   // element-wise f16x2 square
  h2v v = __builtin_bit_cast(h2v, a);
  v = v * v;                                     // v_pk_mul_f16
  return __builtin_bit_cast(unsigned, v);
}
__device__ inline int iclamp(int v, int lo, int hi) {
  return v < lo ? lo : (v > hi ? hi : v);
}

__device__ inline float block_sum256(float v) {
#pragma unroll
  for (int o = 32; o > 0; o >>= 1) v += __shfl_down(v, o, 64);
  __shared__ float r[4];
  if ((threadIdx.x & 63) == 0) r[threadIdx.x >> 6] = v;
  __syncthreads();
  float out = 0.f;
  if (threadIdx.x == 0) {
#pragma unroll
    for (int i = 0; i < 4; ++i) out += r[i];
  }
  __syncthreads();
  return out;
}

__global__ void zero_acc_k(float* acc) {
  if (threadIdx.x < 8) acc[threadIdx.x] = 0.f;
}

__global__ __launch_bounds__(NTHR, 3) void fused_k(
    const float* __restrict__ pred, const float* __restrict__ gt,
    float* __restrict__ acc, KArg ka) {
  __shared__ uint2 sd[SDW];    // staged {S-pair, D-pair}  2.9 KB
  __shared__ uint4 tmp[TMW];   // H-blurred {hS,hD,hS2,hD2} 3.6 KB

  // XCD-aware bijective swizzle (kept from R16: FETCH 257->78 MB)
  int b0 = blockIdx.x;
  int b = (b0 & 7) * ((NB * 1024) >> 3) + (b0 >> 3);
  int tile = b & 1023;               // 32 h-tiles x 32 w-tiles
  int n = b >> 10;
  int th0 = (tile >> 5) * TH;
  int tw0 = (tile & 31) * TW;
  int t = threadIdx.x;

  // ---- stage metadata, slot 0 (item t, always < 338)
  int rp0 = t / SCOLS, x0 = t - rp0 * SCOLS;
  int gx0 = iclamp(tw0 + x0 - 5, 0, WW - 1);
  int go0a = iclamp(th0 + 2 * rp0 - 5, 0, HH - 1) * WW + gx0;
  int go0b = iclamp(th0 + 2 * rp0 - 4, 0, HH - 1) * WW + gx0;
  int w0i = (2 * rp0 + (x0 & 1)) * PW + (x0 >> 1);
  bool ox0 = (x0 >= 5) && (x0 < 5 + TW);
  float o0a = (ox0 && rp0 >= 3 && rp0 <= 10) ? 1.f : 0.f;  // row 2rp-5 owned
  float o0b = (ox0 && rp0 >= 2 && rp0 <= 9) ? 1.f : 0.f;   // row 2rp-4 owned
  // slot 1 (items 256..337 -> threads 174..255)
  int i1 = t + XTRA;
  bool has2 = (i1 >= NTHR);
  int rp1 = i1 / SCOLS, x1 = i1 - rp1 * SCOLS;
  int gx1 = iclamp(tw0 + x1 - 5, 0, WW - 1);
  int go1a = iclamp(th0 + 2 * rp1 - 5, 0, HH - 1) * WW + gx1;
  int go1b = iclamp(th0 + 2 * rp1 - 4, 0, HH - 1) * WW + gx1;
  int w1i = (2 * rp1 + (x1 & 1)) * PW + (x1 >> 1);
  bool ox1 = (x1 >= 5) && (x1 < 5 + TW);
  float o1a = (ox1 && rp1 >= 3 && rp1 <= 10) ? 1.f : 0.f;
  float o1b = (ox1 && rp1 >= 2 && rp1 <= 9) ? 1.f : 0.f;

  // ---- H metadata: item = (out-row-pair hm, col-pair hcp), m-minor
  bool hasH = (t < HITEMS);
  int hm = t & 7, hcp = t >> 3;
  int hrd = hm * PLSTR + hcp;        // plane0 read base (tap J adds J*PLSTR)
  int hwr = (2 * hm) * PW + hcp;     // row 2m write (+PW for row 2m+1)

  // ---- W metadata: thread owns px (t>>4, t&15) -- broadcast-pair reads
  int wx = t & 15;
  int wrd = (t >> 4) * PW + (wx >> 1);
  unsigned cw[6];
#pragma unroll
  for (int J = 0; J < 6; ++J) cw[J] = (wx & 1) ? ka.go[J] : ka.ge[J];

  const float* pb = pred + (size_t)n * VOL;
  const float* qb = gt + (size_t)n * VOL;

  // prefetch slice 0
  float p0a = pb[go0a], p0b = pb[go0b], q0a = qb[go0a], q0b = qb[go0b];
  float p1a = 0.f, p1b = 0.f, q1a = 0.f, q1b = 0.f;
  if (has2) { p1a = pb[go1a]; p1b = pb[go1b]; q1a = qb[go1a]; q1b = qb[go1b]; }

  float psnr = 0.f;
  h2v A01[DD], A23[DD];              // packed {a0,a1} / {a2,a3} accumulators
#pragma unroll
  for (int j = 0; j < DD; ++j) {
    A01[j] = (h2v){(_Float16)0, (_Float16)0};
    A23[j] = (h2v){(_Float16)0, (_Float16)0};
  }

#pragma unroll 1
  for (int d = 0; d < DD; ++d) {
    // ---- stage slice d ({S,D} only; b64 writes)
    {
      float SA = p0a + q0a, DA = p0a - q0a;
      float SB = p0b + q0b, DB = p0b - q0b;
      psnr = fmaf(o0a, DA * DA, psnr);
      psnr = fmaf(o0b, DB * DB, psnr);
      sd[w0i] = make_uint2(pkh(SA, SB), pkh(DA, DB));
    }
    if (has2) {
      float SA = p1a + q1a, DA = p1a - q1a;
      float SB = p1b + q1b, DB = p1b - q1b;
      psnr = fmaf(o1a, DA * DA, psnr);
      psnr = fmaf(o1b, DB * DB, psnr);
      sd[w1i] = make_uint2(pkh(SA, SB), pkh(DA, DB));
    }
    __syncthreads();   // B1: sd ready; also fences tmp vs prev iter's W reads

    // prefetch slice d+1 (hides under H+W; consumed next iter after B2+W)
    if (d < DD - 1) {
      const float* P = pb + (size_t)(d + 1) * SLICE;
      const float* Q = qb + (size_t)(d + 1) * SLICE;
      p0a = P[go0a]; p0b = P[go0b]; q0a = Q[go0a]; q0b = Q[go0b];
      if (has2) { p1a = P[go1a]; p1b = P[go1b]; q1a = Q[go1a]; q1b = Q[go1b]; }
    }

    // ---- H-blur (vertical), fused row parities: 12 b64 reads -> 2 b128
    // writes; squared pairs formed in-register (v_pk_mul_f16)
    if (hasH) {
      float e0[4] = {0, 0, 0, 0}, e1[4] = {0, 0, 0, 0};   // row 2m, col 2cp / 2cp+1
      float r0[4] = {0, 0, 0, 0}, r1[4] = {0, 0, 0, 0};   // row 2m+1
#pragma unroll
      for (int J = 0; J < 6; ++J) {
        uint2 ve = sd[hrd + J * PLSTR];        // col 2cp,  row-pair m+J
        uint2 vo = sd[hrd + J * PLSTR + PW];   // col 2cp+1
        unsigned ves = pk2sq(ve.x), ved = pk2sq(ve.y);
        unsigned vos = pk2sq(vo.x), vod = pk2sq(vo.y);
        unsigned cge = ka.ge[J], cgo = ka.go[J];
        e0[0] = dot2h(cge, ve.x, e0[0]); e0[1] = dot2h(cge, ve.y, e0[1]);
        e0[2] = dot2h(cge, ves, e0[2]);  e0[3] = dot2h(cge, ved, e0[3]);
        r0[0] = dot2h(cgo, ve.x, r0[0]); r0[1] = dot2h(cgo, ve.y, r0[1]);
        r0[2] = dot2h(cgo, ves, r0[2]);  r0[3] = dot2h(cgo, ved, r0[3]);
        e1[0] = dot2h(cge, vo.x, e1[0]); e1[1] = dot2h(cge, vo.y, e1[1]);
        e1[2] = dot2h(cge, vos, e1[2]);  e1[3] = dot2h(cge, vod, e1[3]);
        r1[0] = dot2h(cgo, vo.x, r1[0]); r1[1] = dot2h(cgo, vo.y, r1[1]);
        r1[2] = dot2h(cgo, vos, r1[2]);  r1[3] = dot2h(cgo, vod, r1[3]);
      }
      tmp[hwr] = make_uint4(pkh(e0[0], e1[0]), pkh(e0[1], e1[1]),
                            pkh(e0[2], e1[2]), pkh(e0[3], e1[3]));
      tmp[hwr + PW] = make_uint4(pkh(r0[0], r1[0]), pkh(r0[1], r1[1]),
                                 pkh(r0[2], r1[2]), pkh(r0[3], r1[3]));
    }
    __syncthreads();   // B2: tmp ready; also separates H's sd reads from the
                       // NEXT iteration's stage writes (single buffer safe)

    // ---- W-blur at owned px: 6 b128 reads (2-way broadcast), 24 dot2
    float w0 = 0.f, w1 = 0.f, w2 = 0.f, w3 = 0.f;
#pragma unroll
    for (int J = 0; J < 6; ++J) {
      uint4 v = tmp[wrd + J];
      w0 = dot2h(cw[J], v.x, w0); w1 = dot2h(cw[J], v.y, w1);
      w2 = dot2h(cw[J], v.z, w2); w3 = dot2h(cw[J], v.w, w3);
    }
    // ---- D-accumulate: packed f16 (v_pk_fma_f16), 2 pkh + 32 pk_fma
    h2v p01 = __builtin_bit_cast(h2v, pkh(w0, w1));
    h2v p23 = __builtin_bit_cast(h2v, pkh(w2, w3));
    const unsigned* wl = ka.wl2 + d * DD;   // uniform -> s_load
#pragma unroll
    for (int o = 0; o < DD; ++o) {
      h2v w = __builtin_bit_cast(h2v, wl[o]);
      A01[o] = __builtin_elementwise_fma(w, p01, A01[o]);
      A23[o] = __builtin_elementwise_fma(w, p23, A23[o]);
    }
  }

  // ---- SSIM over the 16 douts of this px
  float ssum = 0.f;
#pragma unroll
  for (int j = 0; j < DD; ++j) {
    float Sb = (float)A01[j].x, Db = (float)A01[j].y;
    float B1 = (float)A23[j].x, B2 = (float)A23[j].y;
    float SS = Sb * Sb, DDm = Db * Db;
    float m12_2 = (SS - DDm) * 0.5f;     // 2*mu1*mu2
    float msq   = (SS + DDm) * 0.5f;     // mu1^2 + mu2^2
    float Epq   = (B1 - B2) * 0.25f;     // E[pq]
    float Esum  = (B1 + B2) * 0.5f;      // E[p^2+q^2]
    float sig12_2 = 2.f * Epq - m12_2;   // 2*sigma12
    float svar    = Esum - msq;          // sigma1^2 + sigma2^2
    float num = (m12_2 + C1F) * (sig12_2 + C2F);
    float den = (msq + C1F) * (svar + C2F);
    ssum += num / den;
  }
  float bs = block_sum256(ssum);
  if (t == 0) atomicAdd(&acc[4 + n], bs);
  float bp = block_sum256(psnr);
  if (t == 0) atomicAdd(&acc[n], bp);
}

__global__ void final_k(const float* __restrict__ acc, float* __restrict__ out) {
  if (threadIdx.x == 0 && blockIdx.x == 0) {
    double psnr = 0.0, ssim = 0.0;
    for (int n = 0; n < NB; ++n) {
      double mse = (double)acc[n] / (double)VOL;
      psnr += 10.0 * log10(1.0 / mse);
      ssim += (double)acc[4 + n] / (double)VOL;
    }
    out[0] = (float)psnr;
    out[1] = (float)ssim;
    out[2] = (float)NB;
  }
}

// host f32 -> f16 (round-to-nearest-even)
static unsigned short f2h(float f) {
  union { float f; unsigned u; } v; v.f = f;
  unsigned u = v.u;
  unsigned s = (u >> 16) & 0x8000u;
  int e = (int)((u >> 23) & 0xff) - 127 + 15;
  unsigned m = u & 0x7fffffu;
  if (e <= 0) return (unsigned short)s;
  if (e >= 31) return (unsigned short)(s | 0x7c00u);
  unsigned h = ((unsigned)e << 10) | (m >> 13);
  unsigned rem = m & 0x1fffu;
  if (rem > 0x1000u || (rem == 0x1000u && (h & 1u))) h++;
  return (unsigned short)(s | h);
}
// host f16 -> f32 (normals + zero)
static float h2f(unsigned short h) {
  unsigned se = (h >> 10) & 0x1f, m = h & 0x3ffu, s = ((unsigned)h & 0x8000u) << 16;
  union { unsigned u; float f; } v;
  if (se == 0) { v.u = s; return v.f; }
  v.u = s | ((se - 15 + 127) << 23) | (m << 13);
  return v.f;
}

extern "C" void kernel_launch(void* const* d_in, const int* in_sizes, int n_in,
                              void* d_out, int out_size, void* d_ws, size_t ws_size,
                              hipStream_t stream) {
  const float* pred = (const float*)d_in[0];
  const float* gt = (const float*)d_in[1];
  float* acc = (float*)d_ws;    // 8 floats

  double tt[11], s = 0.0;
  for (int i = 0; i < 11; ++i) {
    double x = i - 5;
    tt[i] = exp(-(x * x) / 4.5);
    s += tt[i];
  }
  float g[11];
  for (int i = 0; i < 11; ++i) g[i] = (float)(tt[i] / s);

  // f16 taps renormalized so the f16 values sum exactly to 1
  unsigned short hg[11];
  for (int i = 0; i < 11; ++i) hg[i] = f2h(g[i]);
  for (int pass = 0; pass < 3; ++pass) {
    double sum = 0.0;
    for (int i = 0; i < 11; ++i) sum += (double)h2f(hg[i]);
    hg[5] = f2h((float)((double)h2f(hg[5]) + (1.0 - sum)));
  }

  KArg ka;
  // even phase: (g0,g1)(g2,g3)(g4,g5)(g6,g7)(g8,g9)(g10,0)
  for (int j = 0; j < 5; ++j)
    ka.ge[j] = (unsigned)hg[2 * j] | ((unsigned)hg[2 * j + 1] << 16);
  ka.ge[5] = (unsigned)hg[10];
  // odd phase: (0,g0)(g1,g2)(g3,g4)(g5,g6)(g7,g8)(g9,g10)
  ka.go[0] = ((unsigned)hg[0]) << 16;
  for (int j = 1; j < 6; ++j)
    ka.go[j] = (unsigned)hg[2 * j - 1] | ((unsigned)hg[2 * j] << 16);

  // clamp-folded D-blur weights wl[d][o]; f16 per-dout renorm; splat-packed
  float wl[DD][DD];
  for (int o = 0; o < DD; ++o)
    for (int d = 0; d < DD; ++d) {
      float w = 0.f;
      for (int k = 0; k < 11; ++k) {
        int j = o + k - 5;
        j = j < 0 ? 0 : (j > 15 ? 15 : j);
        if (j == d) w += g[k];
      }
      wl[d][o] = w;
    }
  for (int o = 0; o < DD; ++o) {
    unsigned short wv[DD];
    int dmx = 0;
    for (int d = 0; d < DD; ++d) {
      wv[d] = f2h(wl[d][o]);
      if (wl[d][o] > wl[dmx][o]) dmx = d;
    }
    for (int pass = 0; pass < 3; ++pass) {
      double sum = 0.0;
      for (int d = 0; d < DD; ++d) sum += (double)h2f(wv[d]);
      wv[dmx] = f2h((float)((double)h2f(wv[dmx]) + (1.0 - sum)));
    }
    for (int d = 0; d < DD; ++d)
      ka.wl2[d * DD + o] = (unsigned)wv[d] | ((unsigned)wv[d] << 16);
  }

  zero_acc_k<<<1, 64, 0, stream>>>(acc);
  fused_k<<<NB * 1024, NTHR, 0, stream>>>(pred, gt, acc, ka);
  final_k<<<1, 1, 0, stream>>>(acc, (float*)d_out);
}

// Round 16
// 237.232 us; speedup vs baseline: 1.0742x; 1.0065x over previous
//
#include <hip/hip_runtime.h>
#include <cmath>

// PSNR + 3D-SSIM, pred/gt (N=4, C=16->D, H=512, W=512) f32.
// R24 = R23 (141.9us fused -- f16x2 packed accumulators broke the 154us
// occupancy plateau; VGPR 68->52, occ 30->38%) + 2 SLICES PER ITERATION:
//   - sd/tmp get two regions (A: slice dd, B: slice dd+1; 13.2 KB total).
//   - H runs on 208 threads (hs = t&1 selects region) instead of 104:
//     the H phase no longer idles waves 2-3.
//   - Barriers per block: 32 -> 16 (2 per 2 slices).
//   - W + D-accumulate handle both slices between the same barrier pair.
// Per-slice math is R23 byte-identical (b64 {S,D} staging, in-register
// squares, dot2 H/W, f16x2 pk_fma D-acc, XCD swizzle). Race structure is
// the same 2-barrier argument applied to both regions. ~96 total regs
// (64 arch + 32 acc) -- no caps, no mega-unroll.

#define NB 4
#define DD 16
#define HH 512
#define WW 512
#define SLICE (HH * WW)
#define VOL (DD * SLICE)
#define C1F 0.0001f
#define C2F 0.0009f

#define TH 16
#define TW 16
#define SCOLS 26            // staged cols (TW+10)
#define NRP 13              // staged row-pairs ((TH+10)/2)
#define PW 14               // words per col-parity plane (13 + pad)
#define PLSTR 28            // row-pair stride (2 planes)
#define SDW (NRP * PLSTR)   // 364 uint2 per region
#define TMW (TH * PW)       // 224 uint4 per region
#define NTHR 256
#define SIT (NRP * SCOLS)   // 338 stage items per slice
#define XTRA (SIT - NTHR)   // 82
#define HITEMS 104          // 8 out-row-pairs x 13 col-pairs (per slice)

typedef _Float16 h2v __attribute__((ext_vector_type(2)));

struct KArg {
  unsigned ge[6], go[6];   // f16x2 tap-pair coeffs, even/odd phase (renorm'd)
  unsigned wl2[DD * DD];   // [d*16+o] = f16x2 splat (w,w), per-dout renorm'd
};

__device__ inline float dot2h(unsigned a, unsigned b, float c) {
#if __has_builtin(__builtin_amdgcn_fdot2)
  return __builtin_amdgcn_fdot2(__builtin_bit_cast(h2v, a),
                                __builtin_bit_cast(h2v, b), c, false);
#else
  h2v av = __builtin_bit_cast(h2v, a), bv = __builtin_bit_cast(h2v, b);
  return fmaf((float)av.y, (float)bv.y, fmaf((float)av.x, (float)bv.x, c));
#endif
}
__device__ inline unsigned pkh(float a, float b) {
  return __builtin_bit_cast(unsigned, __builtin_amdgcn_cvt_pkrtz(a, b));
}
__device__ inline unsigned pk2sq(unsigned a) {   // element-wise f16x2 square
  h2v v = __builtin_bit_cast(h2v, a);
  v = v * v;                                     // v_pk_mul_f16
  return __builtin_bit_cast(unsigned, v);
}
__device__ inline int iclamp(int v, int lo, int hi) {
  return v < lo ? lo : (v > hi ? hi : v);
}

__device__ inline float block_sum256(float v) {
#pragma unroll
  for (int o = 32; o > 0; o >>= 1) v += __shfl_down(v, o, 64);
  __shared__ float r[4];
  if ((threadIdx.x & 63) == 0) r[threadIdx.x >> 6] = v;
  __syncthreads();
  float out = 0.f;
  if (threadIdx.x == 0) {
#pragma unroll
    for (int i = 0; i < 4; ++i) out += r[i];
  }
  __syncthreads();
  return out;
}

__global__ void zero_acc_k(float* acc) {
  if (threadIdx.x < 8) acc[threadIdx.x] = 0.f;
}

__global__ __launch_bounds__(NTHR, 3) void fused_k(
    const float* __restrict__ pred, const float* __restrict__ gt,
    float* __restrict__ acc, KArg ka) {
  __shared__ uint2 sd[2 * SDW];    // staged {S,D}, regions A|B   5.8 KB
  __shared__ uint4 tmp[2 * TMW];   // H-blurred, regions A|B      7.2 KB

  // XCD-aware bijective swizzle (kept from R16: FETCH 257->78 MB)
  int b0 = blockIdx.x;
  int b = (b0 & 7) * ((NB * 1024) >> 3) + (b0 >> 3);
  int tile = b & 1023;               // 32 h-tiles x 32 w-tiles
  int n = b >> 10;
  int th0 = (tile >> 5) * TH;
  int tw0 = (tile & 31) * TW;
  int t = threadIdx.x;

  // ---- stage metadata, slot 0 (item t, always < 338)
  int rp0 = t / SCOLS, x0 = t - rp0 * SCOLS;
  int gx0 = iclamp(tw0 + x0 - 5, 0, WW - 1);
  int go0a = iclamp(th0 + 2 * rp0 - 5, 0, HH - 1) * WW + gx0;
  int go0b = iclamp(th0 + 2 * rp0 - 4, 0, HH - 1) * WW + gx0;
  int w0i = (2 * rp0 + (x0 & 1)) * PW + (x0 >> 1);
  bool ox0 = (x0 >= 5) && (x0 < 5 + TW);
  float o0a = (ox0 && rp0 >= 3 && rp0 <= 10) ? 1.f : 0.f;  // row 2rp-5 owned
  float o0b = (ox0 && rp0 >= 2 && rp0 <= 9) ? 1.f : 0.f;   // row 2rp-4 owned
  // slot 1 (items 256..337 -> threads 174..255)
  int i1 = t + XTRA;
  bool has2 = (i1 >= NTHR);
  int rp1 = i1 / SCOLS, x1 = i1 - rp1 * SCOLS;
  int gx1 = iclamp(tw0 + x1 - 5, 0, WW - 1);
  int go1a = iclamp(th0 + 2 * rp1 - 5, 0, HH - 1) * WW + gx1;
  int go1b = iclamp(th0 + 2 * rp1 - 4, 0, HH - 1) * WW + gx1;
  int w1i = (2 * rp1 + (x1 & 1)) * PW + (x1 >> 1);
  bool ox1 = (x1 >= 5) && (x1 < 5 + TW);
  float o1a = (ox1 && rp1 >= 3 && rp1 <= 10) ? 1.f : 0.f;
  float o1b = (ox1 && rp1 >= 2 && rp1 <= 9) ? 1.f : 0.f;

  // ---- H metadata: 208 threads; hs = t&1 picks region, item hi = t>>1
  bool hasH = (t < 2 * HITEMS);
  int hs = t & 1, hi = t >> 1;
  int hm = hi & 7, hcp = hi >> 3;
  int hrd = hs * SDW + hm * PLSTR + hcp;   // tap J adds J*PLSTR
  int hwr = hs * TMW + (2 * hm) * PW + hcp;

  // ---- W metadata: thread owns px (t>>4, t&15) -- broadcast-pair reads
  int wx = t & 15;
  int wrd = (t >> 4) * PW + (wx >> 1);
  unsigned cw[6];
#pragma unroll
  for (int J = 0; J < 6; ++J) cw[J] = (wx & 1) ? ka.go[J] : ka.ge[J];

  const float* pb = pred + (size_t)n * VOL;
  const float* qb = gt + (size_t)n * VOL;

  // prefetch slices 0 (A) and 1 (B)
  float pa0a = pb[go0a], pa0b = pb[go0b], qa0a = qb[go0a], qa0b = qb[go0b];
  float pb0a = pb[SLICE + go0a], pb0b = pb[SLICE + go0b];
  float qb0a = qb[SLICE + go0a], qb0b = qb[SLICE + go0b];
  float pa1a = 0.f, pa1b = 0.f, qa1a = 0.f, qa1b = 0.f;
  float pb1a = 0.f, pb1b = 0.f, qb1a = 0.f, qb1b = 0.f;
  if (has2) {
    pa1a = pb[go1a]; pa1b = pb[go1b]; qa1a = qb[go1a]; qa1b = qb[go1b];
    pb1a = pb[SLICE + go1a]; pb1b = pb[SLICE + go1b];
    qb1a = qb[SLICE + go1a]; qb1b = qb[SLICE + go1b];
  }

  float psnr = 0.f;
  h2v A01[DD], A23[DD];              // packed {a0,a1} / {a2,a3} accumulators
#pragma unroll
  for (int j = 0; j < DD; ++j) {
    A01[j] = (h2v){(_Float16)0, (_Float16)0};
    A23[j] = (h2v){(_Float16)0, (_Float16)0};
  }

#pragma unroll 1
  for (int dd = 0; dd < DD; dd += 2) {
    // ---- stage slice A (dd) and slice B (dd+1)
    {
      float SA = pa0a + qa0a, DA = pa0a - qa0a;
      float SB = pa0b + qa0b, DB = pa0b - qa0b;
      psnr = fmaf(o0a, DA * DA, psnr);
      psnr = fmaf(o0b, DB * DB, psnr);
      sd[w0i] = make_uint2(pkh(SA, SB), pkh(DA, DB));
      SA = pb0a + qb0a; DA = pb0a - qb0a;
      SB = pb0b + qb0b; DB = pb0b - qb0b;
      psnr = fmaf(o0a, DA * DA, psnr);
      psnr = fmaf(o0b, DB * DB, psnr);
      sd[SDW + w0i] = make_uint2(pkh(SA, SB), pkh(DA, DB));
    }
    if (has2) {
      float SA = pa1a + qa1a, DA = pa1a - qa1a;
      float SB = pa1b + qa1b, DB = pa1b - qa1b;
      psnr = fmaf(o1a, DA * DA, psnr);
      psnr = fmaf(o1b, DB * DB, psnr);
      sd[w1i] = make_uint2(pkh(SA, SB), pkh(DA, DB));
      SA = pb1a + qb1a; DA = pb1a - qb1a;
      SB = pb1b + qb1b; DB = pb1b - qb1b;
      psnr = fmaf(o1a, DA * DA, psnr);
      psnr = fmaf(o1b, DB * DB, psnr);
      sd[SDW + w1i] = make_uint2(pkh(SA, SB), pkh(DA, DB));
    }
    __syncthreads();   // B1: sd A+B ready; fences tmp vs prev iter's W reads

    // prefetch slices dd+2 (A) and dd+3 (B)
    if (dd < DD - 2) {
      const float* PA = pb + (size_t)(dd + 2) * SLICE;
      const float* QA = qb + (size_t)(dd + 2) * SLICE;
      pa0a = PA[go0a]; pa0b = PA[go0b]; qa0a = QA[go0a]; qa0b = QA[go0b];
      const float* PB = pb + (size_t)(dd + 3) * SLICE;
      const float* QB = qb + (size_t)(dd + 3) * SLICE;
      pb0a = PB[go0a]; pb0b = PB[go0b]; qb0a = QB[go0a]; qb0b = QB[go0b];
      if (has2) {
        pa1a = PA[go1a]; pa1b = PA[go1b]; qa1a = QA[go1a]; qa1b = QA[go1b];
        pb1a = PB[go1a]; pb1b = PB[go1b]; qb1a = QB[go1a]; qb1b = QB[go1b];
      }
    }

    // ---- H-blur on 208 threads (region hs): 12 b64 reads -> 2 b128 writes
    if (hasH) {
      float e0[4] = {0, 0, 0, 0}, e1[4] = {0, 0, 0, 0};   // row 2m, col 2cp/2cp+1
      float r0[4] = {0, 0, 0, 0}, r1[4] = {0, 0, 0, 0};   // row 2m+1
#pragma unroll
      for (int J = 0; J < 6; ++J) {
        uint2 ve = sd[hrd + J * PLSTR];
        uint2 vo = sd[hrd + J * PLSTR + PW];
        unsigned ves = pk2sq(ve.x), ved = pk2sq(ve.y);
        unsigned vos = pk2sq(vo.x), vod = pk2sq(vo.y);
        unsigned cge = ka.ge[J], cgo = ka.go[J];
        e0[0] = dot2h(cge, ve.x, e0[0]); e0[1] = dot2h(cge, ve.y, e0[1]);
        e0[2] = dot2h(cge, ves, e0[2]);  e0[3] = dot2h(cge, ved, e0[3]);
        r0[0] = dot2h(cgo, ve.x, r0[0]); r0[1] = dot2h(cgo, ve.y, r0[1]);
        r0[2] = dot2h(cgo, ves, r0[2]);  r0[3] = dot2h(cgo, ved, r0[3]);
        e1[0] = dot2h(cge, vo.x, e1[0]); e1[1] = dot2h(cge, vo.y, e1[1]);
        e1[2] = dot2h(cge, vos, e1[2]);  e1[3] = dot2h(cge, vod, e1[3]);
        r1[0] = dot2h(cgo, vo.x, r1[0]); r1[1] = dot2h(cgo, vo.y, r1[1]);
        r1[2] = dot2h(cgo, vos, r1[2]);  r1[3] = dot2h(cgo, vod, r1[3]);
      }
      tmp[hwr] = make_uint4(pkh(e0[0], e1[0]), pkh(e0[1], e1[1]),
                            pkh(e0[2], e1[2]), pkh(e0[3], e1[3]));
      tmp[hwr + PW] = make_uint4(pkh(r0[0], r1[0]), pkh(r0[1], r1[1]),
                                 pkh(r0[2], r1[2]), pkh(r0[3], r1[3]));
    }
    __syncthreads();   // B2: tmp A+B ready; separates sd reads from next stage

    // ---- W-blur + D-accumulate, slice A
    {
      float w0 = 0.f, w1 = 0.f, w2 = 0.f, w3 = 0.f;
#pragma unroll
      for (int J = 0; J < 6; ++J) {
        uint4 v = tmp[wrd + J];
        w0 = dot2h(cw[J], v.x, w0); w1 = dot2h(cw[J], v.y, w1);
        w2 = dot2h(cw[J], v.z, w2); w3 = dot2h(cw[J], v.w, w3);
      }
      h2v p01 = __builtin_bit_cast(h2v, pkh(w0, w1));
      h2v p23 = __builtin_bit_cast(h2v, pkh(w2, w3));
      const unsigned* wl = ka.wl2 + dd * DD;   // uniform -> s_load
#pragma unroll
      for (int o = 0; o < DD; ++o) {
        h2v w = __builtin_bit_cast(h2v, wl[o]);
        A01[o] = __builtin_elementwise_fma(w, p01, A01[o]);
        A23[o] = __builtin_elementwise_fma(w, p23, A23[o]);
      }
    }
    // ---- W-blur + D-accumulate, slice B
    {
      float w0 = 0.f, w1 = 0.f, w2 = 0.f, w3 = 0.f;
#pragma unroll
      for (int J = 0; J < 6; ++J) {
        uint4 v = tmp[TMW + wrd + J];
        w0 = dot2h(cw[J], v.x, w0); w1 = dot2h(cw[J], v.y, w1);
        w2 = dot2h(cw[J], v.z, w2); w3 = dot2h(cw[J], v.w, w3);
      }
      h2v p01 = __builtin_bit_cast(h2v, pkh(w0, w1));
      h2v p23 = __builtin_bit_cast(h2v, pkh(w2, w3));
      const unsigned* wl = ka.wl2 + (dd + 1) * DD;
#pragma unroll
      for (int o = 0; o < DD; ++o) {
        h2v w = __builtin_bit_cast(h2v, wl[o]);
        A01[o] = __builtin_elementwise_fma(w, p01, A01[o]);
        A23[o] = __builtin_elementwise_fma(w, p23, A23[o]);
      }
    }
  }

  // ---- SSIM over the 16 douts of this px
  float ssum = 0.f;
#pragma unroll
  for (int j = 0; j < DD; ++j) {
    float Sb = (float)A01[j].x, Db = (float)A01[j].y;
    float B1 = (float)A23[j].x, B2 = (float)A23[j].y;
    float SS = Sb * Sb, DDm = Db * Db;
    float m12_2 = (SS - DDm) * 0.5f;     // 2*mu1*mu2
    float msq   = (SS + DDm) * 0.5f;     // mu1^2 + mu2^2
    float Epq   = (B1 - B2) * 0.25f;     // E[pq]
    float Esum  = (B1 + B2) * 0.5f;      // E[p^2+q^2]
    float sig12_2 = 2.f * Epq - m12_2;   // 2*sigma12
    float svar    = Esum - msq;          // sigma1^2 + sigma2^2
    float num = (m12_2 + C1F) * (sig12_2 + C2F);
    float den = (msq + C1F) * (svar + C2F);
    ssum += num / den;
  }
  float bs = block_sum256(ssum);
  if (t == 0) atomicAdd(&acc[4 + n], bs);
  float bp = block_sum256(psnr);
  if (t == 0) atomicAdd(&acc[n], bp);
}

__global__ void final_k(const float* __restrict__ acc, float* __restrict__ out) {
  if (threadIdx.x == 0 && blockIdx.x == 0) {
    double psnr = 0.0, ssim = 0.0;
    for (int n = 0; n < NB; ++n) {
      double mse = (double)acc[n] / (double)VOL;
      psnr += 10.0 * log10(1.0 / mse);
      ssim += (double)acc[4 + n] / (double)VOL;
    }
    out[0] = (float)psnr;
    out[1] = (float)ssim;
    out[2] = (float)NB;
  }
}

// host f32 -> f16 (round-to-nearest-even)
static unsigned short f2h(float f) {
  union { float f; unsigned u; } v; v.f = f;
  unsigned u = v.u;
  unsigned s = (u >> 16) & 0x8000u;
  int e = (int)((u >> 23) & 0xff) - 127 + 15;
  unsigned m = u & 0x7fffffu;
  if (e <= 0) return (unsigned short)s;
  if (e >= 31) return (unsigned short)(s | 0x7c00u);
  unsigned h = ((unsigned)e << 10) | (m >> 13);
  unsigned rem = m & 0x1fffu;
  if (rem > 0x1000u || (rem == 0x1000u && (h & 1u))) h++;
  return (unsigned short)(s | h);
}
// host f16 -> f32 (normals + zero)
static float h2f(unsigned short h) {
  unsigned se = (h >> 10) & 0x1f, m = h & 0x3ffu, s = ((unsigned)h & 0x8000u) << 16;
  union { unsigned u; float f; } v;
  if (se == 0) { v.u = s; return v.f; }
  v.u = s | ((se - 15 + 127) << 23) | (m << 13);
  return v.f;
}

extern "C" void kernel_launch(void* const* d_in, const int* in_sizes, int n_in,
                              void* d_out, int out_size, void* d_ws, size_t ws_size,
                              hipStream_t stream) {
  const float* pred = (const float*)d_in[0];
  const float* gt = (const float*)d_in[1];
  float* acc = (float*)d_ws;    // 8 floats

  double tt[11], s = 0.0;
  for (int i = 0; i < 11; ++i) {
    double x = i - 5;
    tt[i] = exp(-(x * x) / 4.5);
    s += tt[i];
  }
  float g[11];
  for (int i = 0; i < 11; ++i) g[i] = (float)(tt[i] / s);

  // f16 taps renormalized so the f16 values sum exactly to 1
  unsigned short hg[11];
  for (int i = 0; i < 11; ++i) hg[i] = f2h(g[i]);
  for (int pass = 0; pass < 3; ++pass) {
    double sum = 0.0;
    for (int i = 0; i < 11; ++i) sum += (double)h2f(hg[i]);
    hg[5] = f2h((float)((double)h2f(hg[5]) + (1.0 - sum)));
  }

  KArg ka;
  // even phase: (g0,g1)(g2,g3)(g4,g5)(g6,g7)(g8,g9)(g10,0)
  for (int j = 0; j < 5; ++j)
    ka.ge[j] = (unsigned)hg[2 * j] | ((unsigned)hg[2 * j + 1] << 16);
  ka.ge[5] = (unsigned)hg[10];
  // odd phase: (0,g0)(g1,g2)(g3,g4)(g5,g6)(g7,g8)(g9,g10)
  ka.go[0] = ((unsigned)hg[0]) << 16;
  for (int j = 1; j < 6; ++j)
    ka.go[j] = (unsigned)hg[2 * j - 1] | ((unsigned)hg[2 * j] << 16);

  // clamp-folded D-blur weights wl[d][o]; f16 per-dout renorm; splat-packed
  float wl[DD][DD];
  for (int o = 0; o < DD; ++o)
    for (int d = 0; d < DD; ++d) {
      float w = 0.f;
      for (int k = 0; k < 11; ++k) {
        int j = o + k - 5;
        j = j < 0 ? 0 : (j > 15 ? 15 : j);
        if (j == d) w += g[k];
      }
      wl[d][o] = w;
    }
  for (int o = 0; o < DD; ++o) {
    unsigned short wv[DD];
    int dmx = 0;
    for (int d = 0; d < DD; ++d) {
      wv[d] = f2h(wl[d][o]);
      if (wl[d][o] > wl[dmx][o]) dmx = d;
    }
    for (int pass = 0; pass < 3; ++pass) {
      double sum = 0.0;
      for (int d = 0; d < DD; ++d) sum += (double)h2f(wv[d]);
      wv[dmx] = f2h((float)((double)h2f(wv[dmx]) + (1.0 - sum)));
    }
    for (int d = 0; d < DD; ++d)
      ka.wl2[d * DD + o] = (unsigned)wv[d] | ((unsigned)wv[d] << 16);
  }

  zero_acc_k<<<1, 64, 0, stream>>>(acc);
  fused_k<<<NB * 1024, NTHR, 0, stream>>>(pred, gt, acc, ka);
  final_k<<<1, 1, 0, stream>>>(acc, (float*)d_out);
}